// Round 1
// baseline (709.477 us; speedup 1.0000x reference)
//
#include <hip/hip_runtime.h>

// Problem constants (reference: N = 1048576 samples, C = 128 classes).
// C is hard-required to be 128 by the thread layout below.
#define NUM_C 128

// ws layout (floats): [0..127] colsum, [128..255] counts, [256] picked_sum
__global__ void init_ws_kernel(float* __restrict__ g) {
    for (int i = threadIdx.x; i < 2 * NUM_C + 1; i += blockDim.x) g[i] = 0.0f;
}

// Main single-pass kernel.
// Layout: 256 threads/block. c4 = tid&31 -> which float4 (4 classes) of the
// 128-class row; r = tid>>5 -> which of 8 rows per iteration. A wave reads
// 1 KiB contiguous per iteration (16 B/lane, fully coalesced).
__global__ __launch_bounds__(256) void main_pass_kernel(
    const float* __restrict__ pred,   // [N, 128] log-probs
    const int*   __restrict__ tgt,    // [N]
    float* __restrict__ g_colsum,     // [128]
    float* __restrict__ g_counts,     // [128]
    float* __restrict__ g_pick,       // [1]
    int N, int rows_per_block)
{
    const int tid = threadIdx.x;
    const int c4  = tid & 31;   // float4 index within row (classes 4*c4 .. 4*c4+3)
    const int r   = tid >> 5;   // row slot 0..7

    long long row0    = (long long)blockIdx.x * rows_per_block;
    long long row_end = row0 + rows_per_block;
    if (row_end > N) row_end = N;

    __shared__ int hist[NUM_C];
    for (int i = tid; i < NUM_C; i += blockDim.x) hist[i] = 0;
    __syncthreads();

    float4 acc  = make_float4(0.f, 0.f, 0.f, 0.f);
    float  pick = 0.f;

    const float4* __restrict__ pred4 = (const float4*)pred;

    for (long long row = row0 + r; row < row_end; row += 8) {
        float4 p = pred4[row * (NUM_C / 4) + c4];
        acc.x += __expf(p.x);
        acc.y += __expf(p.y);
        acc.z += __expf(p.z);
        acc.w += __expf(p.w);

        int t = tgt[row];                       // broadcast within row-group
        if ((t >> 2) == c4) {                   // this thread holds pred[row, t]
            const float* pp = (const float*)&p;
            pick += pp[t & 3];
        }
        if (c4 == 0) atomicAdd(&hist[t], 1);    // 8 LDS atomics / block / iter
    }

    // ---- block-level reduction of per-class sums (8 row-slots -> 1) ----
    __shared__ float s_col[256 * 4];
    s_col[tid * 4 + 0] = acc.x;
    s_col[tid * 4 + 1] = acc.y;
    s_col[tid * 4 + 2] = acc.z;
    s_col[tid * 4 + 3] = acc.w;
    __syncthreads();

    if (tid < NUM_C) {
        int cc4 = tid >> 2, k = tid & 3;
        float s = 0.f;
        #pragma unroll
        for (int rr = 0; rr < 8; ++rr)
            s += s_col[(rr * 32 + cc4) * 4 + k];
        atomicAdd(&g_colsum[tid], s);
        atomicAdd(&g_counts[tid], (float)hist[tid]);
    }

    // ---- picked-sum reduction: wave64 shuffle, then cross-wave via LDS ----
    for (int off = 32; off > 0; off >>= 1)
        pick += __shfl_down(pick, off, 64);
    __shared__ float s_pick[4];
    if ((tid & 63) == 0) s_pick[tid >> 6] = pick;
    __syncthreads();
    if (tid == 0)
        atomicAdd(g_pick, s_pick[0] + s_pick[1] + s_pick[2] + s_pick[3]);
}

// out = ( sum_c |counts_c - colsum_c| - picked_sum ) / N
__global__ void finalize_kernel(const float* __restrict__ g_colsum,
                                const float* __restrict__ g_counts,
                                const float* __restrict__ g_pick,
                                float* __restrict__ out, float invN)
{
    int tid = threadIdx.x;  // 128 threads
    float d = fabsf(g_counts[tid] - g_colsum[tid]);
    for (int off = 32; off > 0; off >>= 1)
        d += __shfl_down(d, off, 64);
    __shared__ float s[2];
    if ((tid & 63) == 0) s[tid >> 6] = d;
    __syncthreads();
    if (tid == 0) out[0] = (s[0] + s[1] - g_pick[0]) * invN;
}

extern "C" void kernel_launch(void* const* d_in, const int* in_sizes, int n_in,
                              void* d_out, int out_size, void* d_ws, size_t ws_size,
                              hipStream_t stream) {
    const float* pred = (const float*)d_in[0];   // [N, C] float32 log-probs
    const int*   tgt  = (const int*)d_in[1];     // [N] int32
    float* out = (float*)d_out;

    const int N = in_sizes[1];                   // 1048576
    // in_sizes[0] / N == 128 == NUM_C (layout hard-requires C=128)

    float* ws       = (float*)d_ws;
    float* g_colsum = ws;            // [128]
    float* g_counts = ws + NUM_C;    // [128]
    float* g_pick   = ws + 2 * NUM_C;// [1]

    const int blocks = 2048;                           // 8 blocks/CU
    const int rows_per_block = (N + blocks - 1) / blocks;  // 512

    init_ws_kernel<<<1, 256, 0, stream>>>(ws);
    main_pass_kernel<<<blocks, 256, 0, stream>>>(pred, tgt, g_colsum, g_counts,
                                                 g_pick, N, rows_per_block);
    finalize_kernel<<<1, NUM_C, 0, stream>>>(g_colsum, g_counts, g_pick, out,
                                             1.0f / (float)N);
}

// Round 2
// 700.816 us; speedup vs baseline: 1.0124x; 1.0124x over previous
//
#include <hip/hip_runtime.h>

// Problem: N = 1048576 samples, C = 128 classes (layout hard-requires C=128).
// out = ( sum_c |counts_c - colsum_c| - sum_n pred[n, t_n] ) / N
#define NUM_C 128
#define BLOCK_ROWS 512
#define NBLOCKS 2048

// ws layout (floats): [0..127] colsum, [128..255] counts, [256] picked_sum
__global__ void init_ws_kernel(float* __restrict__ g) {
    for (int i = threadIdx.x; i < 2 * NUM_C + 1; i += blockDim.x) g[i] = 0.0f;
}

// Branchless select of pred[row, t] from the thread's float4 (classes 4*c4..4*c4+3).
__device__ __forceinline__ float pick_from(float4 p, int tc) {
    // tc = t - 4*c4; contributes only when 0 <= tc <= 3
    float v = (tc == 0) ? p.x : 0.0f;
    v += (tc == 1) ? p.y : 0.0f;
    v += (tc == 2) ? p.z : 0.0f;
    v += (tc == 3) ? p.w : 0.0f;
    return v;
}

// 256 threads: c4 = tid&31 -> which float4 of the 128-class row; r = tid>>5 ->
// row slot (8 rows per iteration-group). Wave reads 1 KiB contiguous per load.
__global__ __launch_bounds__(256) void main_pass_kernel(
    const float* __restrict__ pred,   // [N, 128] log-probs
    const int*   __restrict__ tgt,    // [N]
    float* __restrict__ g_colsum,     // [128]
    float* __restrict__ g_counts,     // [128]
    float* __restrict__ g_pick,       // [1]
    int N)
{
    const int tid = threadIdx.x;
    const int c4  = tid & 31;
    const int r   = tid >> 5;
    const int row0 = blockIdx.x * BLOCK_ROWS;
    int rows = N - row0; if (rows > BLOCK_ROWS) rows = BLOCK_ROWS;

    __shared__ int s_tgt[BLOCK_ROWS];
    __shared__ int hist[NUM_C];
    for (int i = tid; i < NUM_C; i += 256) hist[i] = 0;
    __syncthreads();

    // Stage targets once; histogram here (out of the hot loop).
    for (int i = tid; i < rows; i += 256) {
        int t = tgt[row0 + i];
        s_tgt[i] = t;
        atomicAdd(&hist[t], 1);
    }
    __syncthreads();

    const float4* __restrict__ p4 = (const float4*)pred + (long long)row0 * (NUM_C / 4) + c4;
    const int base_c = c4 << 2;

    float4 acc = make_float4(0.f, 0.f, 0.f, 0.f);
    float  pick = 0.f;

    // Unroll x2: rows j and j+8 per iteration -> 2 independent loads in flight.
    int j = r;
    for (; j + 8 < rows; j += 16) {
        float4 a = p4[j * (NUM_C / 4)];
        float4 b = p4[(j + 8) * (NUM_C / 4)];
        acc.x += __expf(a.x) + __expf(b.x);
        acc.y += __expf(a.y) + __expf(b.y);
        acc.z += __expf(a.z) + __expf(b.z);
        acc.w += __expf(a.w) + __expf(b.w);
        pick += pick_from(a, s_tgt[j] - base_c);
        pick += pick_from(b, s_tgt[j + 8] - base_c);
    }
    for (; j < rows; j += 8) {   // generic tail (not taken for N=1M)
        float4 a = p4[j * (NUM_C / 4)];
        acc.x += __expf(a.x);
        acc.y += __expf(a.y);
        acc.z += __expf(a.z);
        acc.w += __expf(a.w);
        pick += pick_from(a, s_tgt[j] - base_c);
    }

    // ---- block-level reduction of per-class sums (8 row-slots -> 1) ----
    __shared__ float s_col[256 * 4];
    s_col[tid * 4 + 0] = acc.x;
    s_col[tid * 4 + 1] = acc.y;
    s_col[tid * 4 + 2] = acc.z;
    s_col[tid * 4 + 3] = acc.w;
    __syncthreads();

    if (tid < NUM_C) {
        int cc4 = tid >> 2, k = tid & 3;
        float s = 0.f;
        #pragma unroll
        for (int rr = 0; rr < 8; ++rr)
            s += s_col[(rr * 32 + cc4) * 4 + k];
        atomicAdd(&g_colsum[tid], s);
        atomicAdd(&g_counts[tid], (float)hist[tid]);
    }

    // ---- picked-sum: wave64 shuffle, then cross-wave via LDS ----
    for (int off = 32; off > 0; off >>= 1)
        pick += __shfl_down(pick, off, 64);
    __shared__ float s_pick[4];
    if ((tid & 63) == 0) s_pick[tid >> 6] = pick;
    __syncthreads();
    if (tid == 0)
        atomicAdd(g_pick, s_pick[0] + s_pick[1] + s_pick[2] + s_pick[3]);
}

__global__ void finalize_kernel(const float* __restrict__ g_colsum,
                                const float* __restrict__ g_counts,
                                const float* __restrict__ g_pick,
                                float* __restrict__ out, float invN)
{
    int tid = threadIdx.x;  // 128 threads
    float d = fabsf(g_counts[tid] - g_colsum[tid]);
    for (int off = 32; off > 0; off >>= 1)
        d += __shfl_down(d, off, 64);
    __shared__ float s[2];
    if ((tid & 63) == 0) s[tid >> 6] = d;
    __syncthreads();
    if (tid == 0) out[0] = (s[0] + s[1] - g_pick[0]) * invN;
}

extern "C" void kernel_launch(void* const* d_in, const int* in_sizes, int n_in,
                              void* d_out, int out_size, void* d_ws, size_t ws_size,
                              hipStream_t stream) {
    const float* pred = (const float*)d_in[0];   // [N, C] float32 log-probs
    const int*   tgt  = (const int*)d_in[1];     // [N] int32
    float* out = (float*)d_out;

    const int N = in_sizes[1];                   // 1048576

    float* ws       = (float*)d_ws;
    float* g_colsum = ws;             // [128]
    float* g_counts = ws + NUM_C;     // [128]
    float* g_pick   = ws + 2 * NUM_C; // [1]

    const int blocks = (N + BLOCK_ROWS - 1) / BLOCK_ROWS;  // 2048 = 8 blocks/CU

    init_ws_kernel<<<1, 256, 0, stream>>>(ws);
    main_pass_kernel<<<blocks, 256, 0, stream>>>(pred, tgt, g_colsum, g_counts,
                                                 g_pick, N);
    finalize_kernel<<<1, NUM_C, 0, stream>>>(g_colsum, g_counts, g_pick, out,
                                             1.0f / (float)N);
}

// Round 3
// 680.163 us; speedup vs baseline: 1.0431x; 1.0304x over previous
//
#include <hip/hip_runtime.h>

// Problem: N = 1048576 samples, C = 128 classes (layout hard-requires C=128).
// out = ( sum_c |counts_c - colsum_c| - sum_n pred[n, t_n] ) / N
#define NUM_C 128
#define BLOCK_ROWS 512

// ws layout (floats): [0..127] colsum, [128..255] counts, [256] picked_sum
__global__ void init_ws_kernel(float* __restrict__ g) {
    for (int i = threadIdx.x; i < 2 * NUM_C + 1; i += blockDim.x) g[i] = 0.0f;
}

// Branchless select of pred[row, t] from the thread's float4 (classes 4*c4..4*c4+3).
__device__ __forceinline__ float pick_from(float4 p, int tc) {
    float v = (tc == 0) ? p.x : 0.0f;
    v += (tc == 1) ? p.y : 0.0f;
    v += (tc == 2) ? p.z : 0.0f;
    v += (tc == 3) ? p.w : 0.0f;
    return v;
}

__device__ __forceinline__ void exp_acc(float4& acc, float4 p) {
    acc.x += __expf(p.x);
    acc.y += __expf(p.y);
    acc.z += __expf(p.z);
    acc.w += __expf(p.w);
}

// 256 threads: c4 = tid&31 -> which float4 of the 128-class row; r = tid>>5 ->
// row slot (8 rows per iteration-group). Each wave-wide load is 1 KiB contiguous.
__global__ __launch_bounds__(256) void main_pass_kernel(
    const float* __restrict__ pred,   // [N, 128] log-probs
    const int*   __restrict__ tgt,    // [N]
    float* __restrict__ g_colsum,     // [128]
    float* __restrict__ g_counts,     // [128]
    float* __restrict__ g_pick,       // [1]
    int N)
{
    const int tid = threadIdx.x;
    const int c4  = tid & 31;
    const int r   = tid >> 5;
    const int row0 = blockIdx.x * BLOCK_ROWS;
    int rows = N - row0; if (rows > BLOCK_ROWS) rows = BLOCK_ROWS;

    __shared__ int s_tgt[BLOCK_ROWS];
    __shared__ int hist[NUM_C];
    for (int i = tid; i < NUM_C; i += 256) hist[i] = 0;
    __syncthreads();

    // Stage targets once; histogram here (out of the hot loop).
    for (int i = tid; i < rows; i += 256) {
        int t = tgt[row0 + i];
        s_tgt[i] = t;
        atomicAdd(&hist[t], 1);
    }
    __syncthreads();

    const float4* __restrict__ p4 = (const float4*)pred + (long long)row0 * (NUM_C / 4) + c4;
    const int base_c = c4 << 2;

    float4 acc = make_float4(0.f, 0.f, 0.f, 0.f);
    float  pick = 0.f;

    // Unroll x4: rows j, j+8, j+16, j+24 -> 4 independent 16B loads in flight.
    int j = r;
    for (; j + 24 < rows; j += 32) {
        float4 a = p4[(j     ) * (NUM_C / 4)];
        float4 b = p4[(j +  8) * (NUM_C / 4)];
        float4 c = p4[(j + 16) * (NUM_C / 4)];
        float4 d = p4[(j + 24) * (NUM_C / 4)];
        int ta = s_tgt[j] - base_c;
        int tb = s_tgt[j +  8] - base_c;
        int tc = s_tgt[j + 16] - base_c;
        int td = s_tgt[j + 24] - base_c;
        exp_acc(acc, a); pick += pick_from(a, ta);
        exp_acc(acc, b); pick += pick_from(b, tb);
        exp_acc(acc, c); pick += pick_from(c, tc);
        exp_acc(acc, d); pick += pick_from(d, td);
    }
    for (; j < rows; j += 8) {   // generic tail (not taken for N=1M)
        float4 a = p4[j * (NUM_C / 4)];
        exp_acc(acc, a);
        pick += pick_from(a, s_tgt[j] - base_c);
    }

    // ---- block-level reduction of per-class sums (8 row-slots -> 1) ----
    __shared__ float s_col[256 * 4];
    s_col[tid * 4 + 0] = acc.x;
    s_col[tid * 4 + 1] = acc.y;
    s_col[tid * 4 + 2] = acc.z;
    s_col[tid * 4 + 3] = acc.w;
    __syncthreads();

    if (tid < NUM_C) {
        int cc4 = tid >> 2, k = tid & 3;
        float s = 0.f;
        #pragma unroll
        for (int rr = 0; rr < 8; ++rr)
            s += s_col[(rr * 32 + cc4) * 4 + k];
        atomicAdd(&g_colsum[tid], s);
        atomicAdd(&g_counts[tid], (float)hist[tid]);
    }

    // ---- picked-sum: wave64 shuffle, then cross-wave via LDS ----
    for (int off = 32; off > 0; off >>= 1)
        pick += __shfl_down(pick, off, 64);
    __shared__ float s_pick[4];
    if ((tid & 63) == 0) s_pick[tid >> 6] = pick;
    __syncthreads();
    if (tid == 0)
        atomicAdd(g_pick, s_pick[0] + s_pick[1] + s_pick[2] + s_pick[3]);
}

__global__ void finalize_kernel(const float* __restrict__ g_colsum,
                                const float* __restrict__ g_counts,
                                const float* __restrict__ g_pick,
                                float* __restrict__ out, float invN)
{
    int tid = threadIdx.x;  // 128 threads
    float d = fabsf(g_counts[tid] - g_colsum[tid]);
    for (int off = 32; off > 0; off >>= 1)
        d += __shfl_down(d, off, 64);
    __shared__ float s[2];
    if ((tid & 63) == 0) s[tid >> 6] = d;
    __syncthreads();
    if (tid == 0) out[0] = (s[0] + s[1] - g_pick[0]) * invN;
}

extern "C" void kernel_launch(void* const* d_in, const int* in_sizes, int n_in,
                              void* d_out, int out_size, void* d_ws, size_t ws_size,
                              hipStream_t stream) {
    const float* pred = (const float*)d_in[0];   // [N, C] float32 log-probs
    const int*   tgt  = (const int*)d_in[1];     // [N] int32
    float* out = (float*)d_out;

    const int N = in_sizes[1];                   // 1048576

    float* ws       = (float*)d_ws;
    float* g_colsum = ws;             // [128]
    float* g_counts = ws + NUM_C;     // [128]
    float* g_pick   = ws + 2 * NUM_C; // [1]

    const int blocks = (N + BLOCK_ROWS - 1) / BLOCK_ROWS;  // 2048 = 8 blocks/CU

    init_ws_kernel<<<1, 256, 0, stream>>>(ws);
    main_pass_kernel<<<blocks, 256, 0, stream>>>(pred, tgt, g_colsum, g_counts,
                                                 g_pick, N);
    finalize_kernel<<<1, NUM_C, 0, stream>>>(g_colsum, g_counts, g_pick, out,
                                             1.0f / (float)N);
}